// Round 10
// baseline (40.731 us; speedup 1.0000x reference)
//
#include <hip/hip_runtime.h>

#define B_SZ 1024
#define F_SZ 512
#define NK   50
#define KD   5
#define C_SZ 250              // NK*KD
#define OUTW 562              // F_SZ + NK
#define PLANE (C_SZ * B_SZ)   // single summed SoA M plane: [c=k*5+d][row]
#define NT   16               // 16 row-tiles of 64
#define TILE 64
#define NPAIRS 136            // NT*(NT+1)/2 unordered tile pairs
#define PART_ELEMS (NK * NT * B_SZ)   // 819200 floats
#define LOG2E 1.44269504088896340736f

// ---------------------------------------------------------------------------
// K1: fused GEMM + copy. grid 640 x 256.
//  blocks [0,512):   M = x@T scaled by log2e, SINGLE SoA plane mp[c][row]
//                    (pair needs one pre-summed plane so its uniform reads
//                    can be scalar loads). rt = blk (2 rows), full K=512.
//                    x block-uniform -> s_loads; T coalesced; float2 store.
//  blocks [512,640): copy x rows into out (float2), 8 rows/block.
// ---------------------------------------------------------------------------
__global__ __launch_bounds__(256) void gemm_copy_kernel(const float* __restrict__ x,
                                                        const float* __restrict__ T,
                                                        float* __restrict__ mp,
                                                        float* __restrict__ out,
                                                        int zero_feat) {
    const int t = threadIdx.x;

    if (blockIdx.x >= 512) {                 // ---- copy path
        const int b = blockIdx.x - 512;      // 0..127
#pragma unroll
        for (int r = 0; r < 8; ++r) {
            const int row = b * 8 + r;
            const float2* src = (const float2*)(x + (size_t)row * F_SZ);
            float2* dst = (float2*)(out + (size_t)row * OUTW);
            dst[t] = src[t];
            if (zero_feat && t < NK) out[(size_t)row * OUTW + F_SZ + t] = 0.0f;
        }
        return;
    }

    // ---- gemm path: 2-row tile, full K
    const int rt = blockIdx.x;               // 0..511
    if (t >= C_SZ) return;                   // no __syncthreads in this path
    const int r0 = rt * 2;

    float acc0 = 0.f, acc1 = 0.f;
    const float* xp = x + (size_t)r0 * F_SZ; // block-uniform base -> s_loads
    const float* Tp = T + t;

#pragma unroll 16
    for (int f = 0; f < F_SZ; ++f) {
        const float tv = Tp[(size_t)f * C_SZ];   // coalesced vector load
        acc0 += xp[f] * tv;                      // uniform -> s_load
        acc1 += xp[F_SZ + f] * tv;
    }

    float2* dst = (float2*)(mp + (size_t)t * B_SZ + r0);   // 8B aligned (r0 even)
    *dst = make_float2(acc0 * LOG2E, acc1 * LOG2E);
}

// ---------------------------------------------------------------------------
// K2: symmetric pairwise features. grid 6800 = 50 k x 136 tile pairs (ti<=tj);
// 256 threads. LDS-pipe unload (round-9 lesson: et+staging = ~22 us/CU of LDS
// pipe vs ~8 us VALU):
//   - j-side "c-vectors" are wave-uniform (jq via readfirstlane) and read
//     straight from global -> s_load_dwordx4 on the scalar pipe. No LDS tile.
//   - column sums computed by RECOMPUTING transposed pairs (e(a,b)=e(b,a)):
//     +176 VALU/wave, -128 LDS ops/wave. Only rowp/colp (1KB) stay in LDS.
// Per pair: 5 v_sub + 4 v_add(abs,abs mods) + v_exp(-s) + v_add acc = 11 VALU.
// NO atomics / fences on the fast path; partials part[k][src_tile][row].
// ---------------------------------------------------------------------------
template <bool ATOMIC>
__global__ __launch_bounds__(256) void pair_kernel(const float* __restrict__ mp,
                                                   float* __restrict__ part,
                                                   float* __restrict__ out) {
    // ---- decode block id -> (k, ti, tj), all scalar-uniform
    const int bid = blockIdx.x;
    const int k = bid / NPAIRS;
    int p = bid - k * NPAIRS;
    int ti = 0;
    while (p >= NT - ti) { p -= NT - ti; ++ti; }
    const int tj = ti + p;

    const int t    = threadIdx.x;
    const int lane = t & 63;
    const int jq   = __builtin_amdgcn_readfirstlane(threadIdx.x >> 6);  // wave-uniform

    __shared__ float rowp[4][TILE];
    __shared__ float colp[4][TILE];

    const float* pk = mp + (size_t)k * (KD * B_SZ);   // [5][1024] for this k
    const int bi = ti * TILE;
    const int bj = tj * TILE;

    // per-lane m registers: rows of ti (i-side) and rows of tj (j-side)
    float mi[KD], mj[KD];
#pragma unroll
    for (int d = 0; d < KD; ++d) {
        mi[d] = pk[d * B_SZ + bi + lane];    // coalesced vector loads
        mj[d] = pk[d * B_SZ + bj + lane];
    }

    const bool diag = (ti == tj);
    float acci = 0.f, accj = 0.f;

#define ESUM(mm, c0v, c1v, c2v, c3v, c4v, C)                                     \
    __builtin_amdgcn_exp2f(-(__builtin_fabsf(mm[0] - c0v.C)                      \
                           + __builtin_fabsf(mm[1] - c1v.C)                      \
                           + __builtin_fabsf(mm[2] - c2v.C)                      \
                           + __builtin_fabsf(mm[3] - c3v.C)                      \
                           + __builtin_fabsf(mm[4] - c4v.C)))

#pragma unroll
    for (int c4 = 0; c4 < 4; ++c4) {
        const int j0 = jq * 16 + c4 * 4;     // wave-uniform -> scalar loads

        // i-side: pairs (i = bi+lane, j = bj+j0..j0+3); c-vectors uniform
        const float4 cj0 = *(const float4*)(pk + 0 * B_SZ + bj + j0);
        const float4 cj1 = *(const float4*)(pk + 1 * B_SZ + bj + j0);
        const float4 cj2 = *(const float4*)(pk + 2 * B_SZ + bj + j0);
        const float4 cj3 = *(const float4*)(pk + 3 * B_SZ + bj + j0);
        const float4 cj4 = *(const float4*)(pk + 4 * B_SZ + bj + j0);
        acci += ESUM(mi, cj0, cj1, cj2, cj3, cj4, x);
        acci += ESUM(mi, cj0, cj1, cj2, cj3, cj4, y);
        acci += ESUM(mi, cj0, cj1, cj2, cj3, cj4, z);
        acci += ESUM(mi, cj0, cj1, cj2, cj3, cj4, w);

        if (!diag) {                         // block-uniform branch
            // j-side (transposed recompute): pairs (i' = bj+lane, j' = bi+j0..)
            const float4 ci0 = *(const float4*)(pk + 0 * B_SZ + bi + j0);
            const float4 ci1 = *(const float4*)(pk + 1 * B_SZ + bi + j0);
            const float4 ci2 = *(const float4*)(pk + 2 * B_SZ + bi + j0);
            const float4 ci3 = *(const float4*)(pk + 3 * B_SZ + bi + j0);
            const float4 ci4 = *(const float4*)(pk + 4 * B_SZ + bi + j0);
            accj += ESUM(mj, ci0, ci1, ci2, ci3, ci4, x);
            accj += ESUM(mj, ci0, ci1, ci2, ci3, ci4, y);
            accj += ESUM(mj, ci0, ci1, ci2, ci3, ci4, z);
            accj += ESUM(mj, ci0, ci1, ci2, ci3, ci4, w);
        }
    }
#undef ESUM

    rowp[jq][lane] = acci;
    if (!diag) colp[jq][lane] = accj;
    __syncthreads();

    if (t < TILE) {
        // rows of tile ti, source tile tj
        const float r = rowp[0][t] + rowp[1][t] + rowp[2][t] + rowp[3][t];
        if (ATOMIC) atomicAdd(&out[(size_t)(bi + t) * OUTW + F_SZ + k], r);
        else        part[(size_t)(k * NT + tj) * B_SZ + bi + t] = r;
    } else if (!diag && t < 2 * TILE) {
        // rows of tile tj, source tile ti (disjoint threads, same sync)
        const int l = t - TILE;
        const float c = colp[0][l] + colp[1][l] + colp[2][l] + colp[3][l];
        if (ATOMIC) atomicAdd(&out[(size_t)(bj + l) * OUTW + F_SZ + k], c);
        else        part[(size_t)(k * NT + ti) * B_SZ + bj + l] = c;
    }
}

// ---------------------------------------------------------------------------
// K3: fold the 16 tile-source partials into out. grid 200 x 256.
// Reads coalesced (lanes contiguous in row); L2-resident.
// ---------------------------------------------------------------------------
__global__ __launch_bounds__(256) void reduce_kernel(const float* __restrict__ part,
                                                     float* __restrict__ out) {
    const int k = blockIdx.x >> 2;
    const int i = ((blockIdx.x & 3) << 8) | threadIdx.x;
    float s = 0.0f;
#pragma unroll
    for (int sp = 0; sp < NT; ++sp)
        s += part[((size_t)(k * NT + sp)) * B_SZ + i];
    out[(size_t)i * OUTW + F_SZ + k] = s;
}

// ---------------------------------------------------------------------------
extern "C" void kernel_launch(void* const* d_in, const int* in_sizes, int n_in,
                              void* d_out, int out_size, void* d_ws, size_t ws_size,
                              hipStream_t stream) {
    const float* x = (const float*)d_in[0];   // [1024, 512]
    const float* T = (const float*)d_in[1];   // [512, 250]
    float* out = (float*)d_out;               // [1024, 562]
    float* mp  = (float*)d_ws;                // summed SoA plane [250][1024]
    float* part = mp + (size_t)PLANE;         // [50][16][1024]

    const size_t need = (size_t)(PLANE + PART_ELEMS) * 4;   // 4.3 MB
    const int fast = (ws_size >= need);

    gemm_copy_kernel<<<640, 256, 0, stream>>>(x, T, mp, out, fast ? 0 : 1);

    if (fast) {
        pair_kernel<false><<<NK * NPAIRS, 256, 0, stream>>>(mp, part, out);
        reduce_kernel<<<200, 256, 0, stream>>>(part, out);
    } else {
        pair_kernel<true><<<NK * NPAIRS, 256, 0, stream>>>(mp, nullptr, out);
    }
}